// Round 4
// baseline (10.074 us; speedup 1.0000x reference)
//
#include <hip/hip_runtime.h>

#define NB 4
#define N_IN 1024
#define N_OUT 1024
#define IN_CH_RAW 7
#define CH 8
#define OUT_CH 16
#define LOG2E 1.4426950408889634f

typedef float v2f __attribute__((ext_vector_type(2)));

// Full-wave sum via DPP (no LDS traffic): row_shr 1/2/4/8 + row_bcast 15/31.
__device__ __forceinline__ float wave_sum(float x) {
    float s = x;
    int v;
    v = __builtin_amdgcn_update_dpp(0, __float_as_int(s), 0x111, 0xF, 0xF, true); s += __int_as_float(v);
    v = __builtin_amdgcn_update_dpp(0, __float_as_int(s), 0x112, 0xF, 0xF, true); s += __int_as_float(v);
    v = __builtin_amdgcn_update_dpp(0, __float_as_int(s), 0x114, 0xF, 0xF, true); s += __int_as_float(v);
    v = __builtin_amdgcn_update_dpp(0, __float_as_int(s), 0x118, 0xF, 0xF, true); s += __int_as_float(v);
    v = __builtin_amdgcn_update_dpp(0, __float_as_int(s), 0x142, 0xF, 0xF, true); s += __int_as_float(v);
    v = __builtin_amdgcn_update_dpp(0, __float_as_int(s), 0x143, 0xF, 0xF, true); s += __int_as_float(v);
    return __int_as_float(__builtin_amdgcn_readlane(__float_as_int(s), 63));
}

// 512 blocks x 256 threads; block bi handles 8 output points (4 waves x 2).
// LDS rows {x,y0..y6} packed as 2 float4, slot-XOR swizzled (row bit2 ->
// granule bit0) so stride-32B ds_read_b128 spreads over all 8 bank-groups.
__global__ __launch_bounds__(256) void convdeepset_kernel(
    const float* __restrict__ cx,     // (B, N_IN, 1)
    const float* __restrict__ cy,     // (B, N_IN, 7)
    const float* __restrict__ t,      // (B, N_OUT, 1)
    const float* __restrict__ sigma,  // (8,)
    const float* __restrict__ W,      // (8, 16)
    const float* __restrict__ bias,   // (16,)
    float* __restrict__ out)          // (B, N_OUT, 16)
{
    __shared__ float4 lds4[N_IN * 2];   // 32 KB

    const int tid = threadIdx.x;
    const int bi  = blockIdx.x;
    const int b   = bi >> 7;            // 128 blocks per batch

    // ---- stage: each thread owns 4 rows; 7x dwordx4 + 1 float4, repack, 8x b128 ----
    {
        const float4* cyv = reinterpret_cast<const float4*>(
            cy + (size_t)b * N_IN * IN_CH_RAW + tid * 28);   // 112 B/thread, 16B-aligned
        float4 f[7];
        #pragma unroll
        for (int k = 0; k < 7; ++k) f[k] = cyv[k];
        const float4 xv = *reinterpret_cast<const float4*>(cx + b * N_IN + 4 * tid);
        const float xarr[4] = {xv.x, xv.y, xv.z, xv.w};
        const float* yf = reinterpret_cast<const float*>(f);  // fully-unrolled const idx
        #pragma unroll
        for (int j = 0; j < 4; ++j) {
            const float* yr = yf + 7 * j;
            const int idx = (8 * tid + 2 * j) ^ (tid & 1);    // = 2r ^ ((r&4)>>2), r=4*tid+j
            lds4[idx]     = make_float4(xarr[j], yr[0], yr[1], yr[2]);
            lds4[idx ^ 1] = make_float4(yr[3], yr[4], yr[5], yr[6]);
        }
    }

    // ---- per-thread constants from sigma (overlaps staging latency) ----
    const float s0 = sigma[0];
    bool uni = true;
    float kc2[CH];
    #pragma unroll
    for (int c = 0; c < CH; ++c) {
        const float sc = sigma[c];
        kc2[c] = -0.5f * LOG2E * __expf(-2.0f * sc);
        uni = uni && (sc == s0);
    }
    const float ks = __expf(-s0) * sqrtf(0.5f * LOG2E);

    const int wave = tid >> 6;
    const int lane = tid & 63;
    const int p0   = bi * 8 + wave * 2;
    const int o0   = p0 & (N_OUT - 1);
    const float t0 = t[b * N_OUT + o0];
    const float t1 = t[b * N_OUT + o0 + 1];
    const v2f ks2  = {ks, ks};
    const v2f ntk  = {-(t0 * ks), -(t1 * ks)};

    // fixed per-lane swizzled slots; k-iters differ by +128 slots (2048 B imm)
    const int slot0 = (lane * 2) ^ ((lane & 4) >> 2);
    const int slot1 = slot0 ^ 1;

    v2f acc2[CH];
    #pragma unroll
    for (int c = 0; c < CH; ++c) acc2[c] = (v2f){0.0f, 0.0f};

    __syncthreads();

    if (uni) {
        // fast path: one exp weight per (row, point), packed fp32 math
        #pragma unroll
        for (int k = 0; k < 16; ++k) {
            const float4 q0 = lds4[slot0 + 128 * k];
            const float4 q1 = lds4[slot1 + 128 * k];
            const v2f xx = {q0.x, q0.x};
            const v2f d  = xx * ks2 + ntk;          // v_pk_fma_f32
            const v2f nd2 = -(d * d);               // v_pk_mul_f32 (+neg mod)
            const v2f w  = {exp2f(nd2.x), exp2f(nd2.y)};
            acc2[0] += w;                           // v_pk_add_f32
            acc2[1] += w * q0.y;                    // v_pk_fma_f32 (scalar bcast)
            acc2[2] += w * q0.z;
            acc2[3] += w * q0.w;
            acc2[4] += w * q1.x;
            acc2[5] += w * q1.y;
            acc2[6] += w * q1.z;
            acc2[7] += w * q1.w;
        }
    } else {
        // general path: per-channel scales
        #pragma unroll 2
        for (int k = 0; k < 16; ++k) {
            const float4 q0 = lds4[slot0 + 128 * k];
            const float4 q1 = lds4[slot1 + 128 * k];
            const float y[IN_CH_RAW] = {q0.y, q0.z, q0.w, q1.x, q1.y, q1.z, q1.w};
            const float dx0 = q0.x - t0, d20 = dx0 * dx0;
            const float dx1 = q0.x - t1, d21 = dx1 * dx1;
            acc2[0] += (v2f){exp2f(d20 * kc2[0]), exp2f(d21 * kc2[0])};
            #pragma unroll
            for (int c = 1; c < CH; ++c)
                acc2[c] += (v2f){exp2f(d20 * kc2[c]) * y[c - 1],
                                 exp2f(d21 * kc2[c]) * y[c - 1]};
        }
    }

    // ---- DPP wave reduction: results wave-uniform ----
    float r0[CH], r1[CH];
    #pragma unroll
    for (int c = 0; c < CH; ++c) {
        r0[c] = wave_sum(acc2[c].x);
        r1[c] = wave_sum(acc2[c].y);
    }

    // ---- normalize + linear head: lanes 0-15 -> p0, 16-31 -> p0+1 ----
    if (lane < 32) {
        const int sel = lane >> 4;
        const int col = lane & 15;
        float a[CH];
        #pragma unroll
        for (int c = 0; c < CH; ++c) a[c] = sel ? r1[c] : r0[c];
        const float inv = 1.0f / (a[0] + 1e-8f);
        float v = bias[col] + a[0] * W[col];
        #pragma unroll
        for (int c = 1; c < CH; ++c) v += (a[c] * inv) * W[c * OUT_CH + col];
        out[(size_t)(p0 + sel) * OUT_CH + col] = v;
    }
}

extern "C" void kernel_launch(void* const* d_in, const int* in_sizes, int n_in,
                              void* d_out, int out_size, void* d_ws, size_t ws_size,
                              hipStream_t stream) {
    const float* cx    = (const float*)d_in[0];
    const float* cy    = (const float*)d_in[1];
    const float* t     = (const float*)d_in[2];
    const float* sigma = (const float*)d_in[3];
    const float* W     = (const float*)d_in[4];
    const float* bias  = (const float*)d_in[5];
    float* out = (float*)d_out;

    dim3 grid(NB * N_OUT / 8), block(256);
    convdeepset_kernel<<<grid, block, 0, stream>>>(cx, cy, t, sigma, W, bias, out);
}